// Round 24
// baseline (228.354 us; speedup 1.0000x reference)
//
#include <hip/hip_runtime.h>
#include <math.h>

// ---------------------------------------------------------------------------
// GlobalSubSampleAttn round 24:
//  - gemm_qzw2ln v2: BM=64, grid 1024 (was BM=128/512 blocks @ occupancy 19%,
//    latency-bound: Mfma 11 / VALU 28 / HBM 4.5).  8 waves x 32-col slice
//    (= exactly 1 head each -> cleaner Z-reduce), acc[4][2] x2 stages
//    (~80 VGPR vs 116), LDS 44KB.  2x resident waves to hide barrier chain.
//  - everything else unchanged from round 23 (216.7 us best)
// B=4, N=16384, C=256, S=4096, NHEAD=8, D=32
// ---------------------------------------------------------------------------

#define EP_NONE  0
#define EP_BIAS  1
#define EP_ELU1  2
#define EP_SCALE 3
#define EP_RELU  4
#define EP_KV    5

#define GA_PLAIN  0
#define GA_CONV   1
#define GA_CONCAT 2

typedef __attribute__((ext_vector_type(8))) short short8v;   // 8 bf16
typedef __attribute__((ext_vector_type(4))) float f32x4;

__device__ inline short f2bf(float f) {
    unsigned u = __float_as_uint(f);
    u += 0x7FFFu + ((u >> 16) & 1u);      // round-to-nearest-even
    return (short)(u >> 16);
}
__device__ inline float bf2f(short s) {
    return __uint_as_float(((unsigned)(unsigned short)s) << 16);
}
__device__ inline float fexp(float x) {           // fast e^x (x<=0 here)
    return __builtin_amdgcn_exp2f(x * 1.44269504f);
}
__device__ inline float frcp(float x) {           // fast 1/x
    return __builtin_amdgcn_rcpf(x);
}

__device__ inline void gload16(const void* g, void* l) {
    __builtin_amdgcn_global_load_lds(
        (const __attribute__((address_space(1))) void*)g,
        (__attribute__((address_space(3))) void*)l, 16, 0, 0);
}

template<int EPI>
__device__ inline float epilogue(float c, float b, float scale) {
    if (EPI == EP_BIAS)  return c + b;
    if (EPI == EP_ELU1)  return c > 0.f ? c + 1.f : fexp(c);   // elu(c)+1
    if (EPI == EP_SCALE) return c * scale;
    if (EPI == EP_RELU)  return fmaxf(c, 0.f);
    return c;
}

// XCD-chunked bijective swizzle (nwg % 8 == 0 for all our grids)
__device__ inline int xcd_swz(int lid, int nwg) {
    return (lid & 7) * (nwg >> 3) + (lid >> 3);
}

// weights -> bf16 Bt form (bid 0..3327) + x -> bf16 (bid 3328..5375)
__global__ __launch_bounds__(256) void prep_all(
    const float* __restrict__ srw, const float* __restrict__ wq,
    const float* __restrict__ wk,  const float* __restrict__ wv,
    const float* __restrict__ w1,  const float* __restrict__ w2,
    const float* __restrict__ x,
    short* __restrict__ Wct, short* __restrict__ Wqt, short* __restrict__ Wkt,
    short* __restrict__ Wvt, short* __restrict__ W1t, short* __restrict__ W2t,
    short* __restrict__ xb16)
{
    int bid = blockIdx.x, tid = threadIdx.x;
    if (bid < 1024) {                       // conv: [o][k=p*256+ci]
        int idx = bid * 256 + tid;
        int k = idx & 1023, o = idx >> 10;
        int p = k >> 8, ci = k & 255;
        Wct[idx] = f2bf(srw[(o << 10) + (ci << 2) + p]);
    } else if (bid < 1792) {                // wq/wk/wv: [n][k] 256x256
        int which = (bid - 1024) >> 8;
        int idx = ((bid - 1024) & 255) * 256 + tid;
        int n = idx >> 8, k = idx & 255;
        const float* W = which == 0 ? wq : (which == 1 ? wk : wv);
        short* Wt = which == 0 ? Wqt : (which == 1 ? Wkt : Wvt);
        Wt[idx] = f2bf(W[k * 256 + n]);
    } else if (bid < 2816) {                // mlp_w1: [n][k] 512x512
        int idx = (bid - 1792) * 256 + tid;
        int n = idx >> 9, k = idx & 511;
        W1t[idx] = f2bf(w1[k * 512 + n]);
    } else if (bid < 3328) {                // mlp_w2: [n][k] 256x512
        int idx = (bid - 2816) * 256 + tid;
        int n = idx >> 9, k = idx & 511;
        W2t[idx] = f2bf(w2[k * 256 + n]);
    } else {                                // x cast: 2048 blocks, 8 f4/thread
        int cb = bid - 3328;
        #pragma unroll
        for (int j = 0; j < 8; j++) {
            int idx = cb * 2048 + j * 256 + tid;
            float4 v = reinterpret_cast<const float4*>(x)[idx];
            short4 s;
            s.x = f2bf(v.x); s.y = f2bf(v.y);
            s.z = f2bf(v.z); s.w = f2bf(v.w);
            reinterpret_cast<short4*>(xb16)[idx] = s;
        }
    }
}

// W2a[b][n][k=h*32+d] = sum_v KV[b,h,d,v] * wm[h*32+v, n]   (bf16 Bt form)
__global__ __launch_bounds__(256) void w2_prep(
    const float* __restrict__ KVb, const float* __restrict__ wm,
    short* __restrict__ W2a)
{
    int b = blockIdx.x >> 8, n = blockIdx.x & 255;
    int tid = threadIdx.x;                 // = k
    __shared__ float wcol[256];
    wcol[tid] = wm[tid * 256 + n];
    __syncthreads();
    int h = tid >> 5, d = tid & 31;
    const float* kv = &KVb[b * 8192 + h * 1024 + d * 32];
    float s = 0.f;
    #pragma unroll
    for (int v = 0; v < 32; v++) s = fmaf(kv[v], wcol[h * 32 + v], s);
    W2a[((size_t)(b * 256 + n) << 8) + tid] = f2bf(s);
}

// ---------------------------------------------------------------------------
// gemm_core v2 (round-14 proven): 512 threads, BM=256 x BN=128, 8 waves.
// LDS: A [256][64] 32KB + B [128][64] 16KB.  Swizzled gload_lds + ds_read.
// ---------------------------------------------------------------------------
template<int GATHER, int BB>
__device__ inline void gemm_core(
    const short* __restrict__ Ab, const short* __restrict__ A2b,
    const short* __restrict__ Bt, int K, int bm, int bn,
    short* AlF, short* BlF, f32x4 acc[4][4])
{
    const int tid  = threadIdx.x;          // 0..511
    const int lane = tid & 63;
    const int wave = tid >> 6;             // 0..7
    const int wr   = (wave >> 1) * 64;     // 0,64,128,192
    const int wc   = (wave & 1) * 64;      // 0,64
    const int l15  = lane & 15;
    const int kg   = lane >> 4;
    const int srow = tid >> 3;             // 0..63
    const int sc   = tid & 7;

    if (BB) Bt += (size_t)(bm >> 14) << 16;

    for (int k0 = 0; k0 < K; k0 += 64) {
        __syncthreads();
        #pragma unroll
        for (int q = 0; q < 4; q++) {      // A: 256 rows
            int row = q * 64 + srow;
            int cp  = sc ^ (row & 7);
            const short* ga;
            if (GATHER == GA_PLAIN) {
                ga = Ab + (size_t)(bm + row) * K + k0 + cp * 8;
            } else if (GATHER == GA_CONCAT) {
                const short* base = (k0 < 256) ? Ab : A2b;
                ga = base + ((size_t)(bm + row) << 8) + (k0 & 255) + cp * 8;
            } else { // GA_CONV
                int grow = bm + row;
                int b = grow >> 12, s = grow & 4095;
                int ii = s >> 6, jj = s & 63;
                int p = k0 >> 8;
                int kh = p >> 1, kw = p & 1;
                int pix = (b << 14) + ((2 * ii + kh) << 7) + (2 * jj + kw);
                ga = Ab + ((size_t)pix << 8) + (k0 & 255) + cp * 8;
            }
            gload16(ga, &AlF[(q * 512 + wave * 64) * 8]);
        }
        #pragma unroll
        for (int q = 0; q < 2; q++) {      // B: 128 rows
            int row = q * 64 + srow;
            int cp  = sc ^ (row & 7);
            const short* gb = Bt + (size_t)(bn + row) * K + k0 + cp * 8;
            gload16(gb, &BlF[(q * 512 + wave * 64) * 8]);
        }
        __syncthreads();

        #pragma unroll
        for (int ks = 0; ks < 2; ks++) {
            short8v afr[4], bfr[4];
            #pragma unroll
            for (int m = 0; m < 4; m++) {
                int R = wr + m * 16 + l15;
                afr[m] = *reinterpret_cast<const short8v*>(
                    &AlF[R * 64 + (((ks * 4 + kg) ^ (R & 7)) * 8)]);
            }
            #pragma unroll
            for (int n = 0; n < 4; n++) {
                int R = wc + n * 16 + l15;
                bfr[n] = *reinterpret_cast<const short8v*>(
                    &BlF[R * 64 + (((ks * 4 + kg) ^ (R & 7)) * 8)]);
            }
            #pragma unroll
            for (int m = 0; m < 4; m++)
                #pragma unroll
                for (int n = 0; n < 4; n++)
                    acc[m][n] = __builtin_amdgcn_mfma_f32_16x16x32_bf16(
                        afr[m], bfr[n], acc[m][n], 0, 0, 0);
        }
    }
}

// generic 256x128 GEMM, bf16 output, XCD-swizzled block order (cols fastest)
template<int GATHER, int EPI, int BB>
__global__ __launch_bounds__(512) void gemm_bf16(
    const short* __restrict__ Ab, const short* __restrict__ A2b,
    const short* __restrict__ Bt, const float* __restrict__ bias,
    short* __restrict__ Cb, int N, int K, float scale)
{
    __shared__ short AlF[16384];   // [256][64]
    __shared__ short BlF[8192];    // [128][64]
    const int nwg = gridDim.x * gridDim.y;
    const int lid = blockIdx.y * gridDim.x + blockIdx.x;
    const int swz = xcd_swz(lid, nwg);
    const int bn  = (swz % gridDim.x) * 128;   // col = fast index
    const int bm  = (swz / gridDim.x) * 256;
    f32x4 acc[4][4];
    #pragma unroll
    for (int m = 0; m < 4; m++)
        #pragma unroll
        for (int n = 0; n < 4; n++)
            acc[m][n] = (f32x4){0.f, 0.f, 0.f, 0.f};

    gemm_core<GATHER, BB>(Ab, A2b, Bt, K, bm, bn, AlF, BlF, acc);

    const int lane = threadIdx.x & 63;
    const int wave = threadIdx.x >> 6;
    const int wr = (wave >> 1) * 64, wc = (wave & 1) * 64;
    const int l15 = lane & 15, r0 = (lane >> 4) * 4;
    #pragma unroll
    for (int n = 0; n < 4; n++) {
        int col = bn + wc + n * 16 + l15;
        float bb = (EPI == EP_BIAS) ? bias[col] : 0.f;
        #pragma unroll
        for (int m = 0; m < 4; m++) {
            int rowb = bm + wr + m * 16 + r0;
            #pragma unroll
            for (int j = 0; j < 4; j++) {
                float c = acc[m][n][j];
                float o;
                if (EPI == EP_KV)
                    o = (bn < 256) ? (c > 0.f ? c + 1.f : fexp(c)) : c * scale;
                else
                    o = epilogue<EPI>(c, bb, scale);
                Cb[(size_t)(rowb + j) * N + col] = f2bf(o);
            }
        }
    }
}

// ---------------------------------------------------------------------------
// gemm_ln v5: 512 threads, BN=256 (full row) + fused LayerNorm epilogue.
//   BM64=0: BM=128, 8 waves (2 row x 4 col), acc[4][4]   (mlp2)
//   BM64=1: BM=64,  8 waves (1 row x 8 col-32), acc[4][2] (conv: grid 2x)
//   FIN=0: out bf16 = LN(acc[+bias]);  FIN=1: out f32 = LN(acc)+bf2f(res16)
// ---------------------------------------------------------------------------
template<int GATHER, int BB, int FIN, int BIAS, int BM64>
__global__ __launch_bounds__(512) void gemm_ln(
    const short* __restrict__ Ab, const short* __restrict__ Bt,
    const float* __restrict__ bias,
    const float* __restrict__ g, const float* __restrict__ bv,
    const short* __restrict__ res16, void* __restrict__ Co, int K)
{
    constexpr int BM  = BM64 ? 64 : 128;
    constexpr int NFR = BM64 ? 2 : 4;          // col frags per wave
    constexpr int NW  = BM64 ? 8 : 4;          // waves sharing a row
    __shared__ short Al[BM * 64];              // [BM][64]
    __shared__ short Bl[16384];                // [256][64]
    __shared__ float redS[NW][BM], redQ[NW][BM];
    const int tid  = threadIdx.x;
    const int lane = tid & 63;
    const int wave = tid >> 6;                 // 0..7
    const int wr   = BM64 ? 0 : (wave >> 2) * 64;
    const int wcid = BM64 ? wave : (wave & 3);
    const int cw   = BM64 ? 32 : 64;           // cols per wave
    const int l15  = lane & 15;
    const int kg   = lane >> 4;
    const int srow = tid >> 3;                 // 0..63
    const int sc   = tid & 7;
    const int bm   = blockIdx.x * BM;
    const short* Bp = BB ? Bt + ((size_t)(bm >> 14) << 16) : Bt;

    f32x4 acc[4][NFR];
    #pragma unroll
    for (int m = 0; m < 4; m++)
        #pragma unroll
        for (int n = 0; n < NFR; n++)
            acc[m][n] = (f32x4){0.f, 0.f, 0.f, 0.f};

    for (int k0 = 0; k0 < K; k0 += 64) {
        __syncthreads();
        #pragma unroll
        for (int q = 0; q < BM / 64; q++) {    // A: BM rows
            int row = q * 64 + srow;
            int cp  = sc ^ (row & 7);
            const short* ga;
            if (GATHER == GA_CONV) {
                int grow = bm + row;
                int b = grow >> 12, s = grow & 4095;
                int ii = s >> 6, jj = s & 63;
                int p = k0 >> 8;
                int kh = p >> 1, kw = p & 1;
                int pix = (b << 14) + ((2 * ii + kh) << 7) + (2 * jj + kw);
                ga = Ab + ((size_t)pix << 8) + (k0 & 255) + cp * 8;
            } else {
                ga = Ab + (size_t)(bm + row) * K + k0 + cp * 8;
            }
            gload16(ga, &Al[(q * 512 + wave * 64) * 8]);
        }
        #pragma unroll
        for (int q = 0; q < 4; q++) {          // B: 256 rows
            int row = q * 64 + srow;
            int cp  = sc ^ (row & 7);
            gload16(Bp + (size_t)row * K + k0 + cp * 8,
                    &Bl[(q * 512 + wave * 64) * 8]);
        }
        __syncthreads();

        #pragma unroll
        for (int ks = 0; ks < 2; ks++) {
            short8v afr[4], bfr[NFR];
            #pragma unroll
            for (int m = 0; m < 4; m++) {
                int R = wr + m * 16 + l15;
                afr[m] = *reinterpret_cast<const short8v*>(
                    &Al[R * 64 + (((ks * 4 + kg) ^ (R & 7)) * 8)]);
            }
            #pragma unroll
            for (int n = 0; n < NFR; n++) {
                int R = wcid * cw + n * 16 + l15;
                bfr[n] = *reinterpret_cast<const short8v*>(
                    &Bl[R * 64 + (((ks * 4 + kg) ^ (R & 7)) * 8)]);
            }
            #pragma unroll
            for (int m = 0; m < 4; m++)
                #pragma unroll
                for (int n = 0; n < NFR; n++)
                    acc[m][n] = __builtin_amdgcn_mfma_f32_16x16x32_bf16(
                        afr[m], bfr[n], acc[m][n], 0, 0, 0);
        }
    }

    // ---- optional bias (pre-LN) ----
    if (BIAS) {
        #pragma unroll
        for (int n = 0; n < NFR; n++) {
            float bb = bias[wcid * cw + n * 16 + l15];
            #pragma unroll
            for (int m = 0; m < 4; m++)
                #pragma unroll
                for (int j = 0; j < 4; j++)
                    acc[m][n][j] += bb;
        }
    }

    // ---- fused LayerNorm epilogue ----
    #pragma unroll
    for (int m = 0; m < 4; m++)
        #pragma unroll
        for (int j = 0; j < 4; j++) {
            float s1 = 0.f, s2 = 0.f;
            #pragma unroll
            for (int n = 0; n < NFR; n++) {
                float v = acc[m][n][j];
                s1 += v; s2 += v * v;
            }
            s1 += __shfl_xor(s1, 1, 64); s2 += __shfl_xor(s2, 1, 64);
            s1 += __shfl_xor(s1, 2, 64); s2 += __shfl_xor(s2, 2, 64);
            s1 += __shfl_xor(s1, 4, 64); s2 += __shfl_xor(s2, 4, 64);
            s1 += __shfl_xor(s1, 8, 64); s2 += __shfl_xor(s2, 8, 64);
            if (l15 == 0) {
                int row = wr + m * 16 + kg * 4 + j;
                redS[wcid][row] = s1;
                redQ[wcid][row] = s2;
            }
        }
    __syncthreads();

    float gc[NFR], bc[NFR];
    #pragma unroll
    for (int n = 0; n < NFR; n++) {
        int col = wcid * cw + n * 16 + l15;
        gc[n] = g[col]; bc[n] = bv[col];
    }
    #pragma unroll
    for (int m = 0; m < 4; m++)
        #pragma unroll
        for (int j = 0; j < 4; j++) {
            int row = wr + m * 16 + kg * 4 + j;
            float s1 = 0.f, s2 = 0.f;
            #pragma unroll
            for (int w = 0; w < NW; w++) { s1 += redS[w][row]; s2 += redQ[w][row]; }
            float mean = s1 * (1.f / 256.f);
            float var  = s2 * (1.f / 256.f) - mean * mean;
            float inv  = rsqrtf(var + 1e-5f);
            #pragma unroll
            for (int n = 0; n < NFR; n++) {
                int col = wcid * cw + n * 16 + l15;
                float o = (acc[m][n][j] - mean) * inv * gc[n] + bc[n];
                size_t gi = (size_t)(bm + row) * 256 + col;
                if (FIN) ((float*)Co)[gi] = o + bf2f(res16[gi]);
                else     ((short*)Co)[gi] = f2bf(o);
            }
        }
}

// ---------------------------------------------------------------------------
// gemm_qzw2ln v2: FUSED  Qz = Z.*(elu(x@Wqt)+1)  ->  P = Qz @ W2a[b]  -> LN1
// 512 threads, BM=64 rows/block (grid 1024), BN=256, 8 waves x 32-col slice
// (wave == head).  acc[4][2] per stage; LDS 44KB.
// ---------------------------------------------------------------------------
__global__ __launch_bounds__(512) void gemm_qzw2ln(
    const short* __restrict__ xb, const short* __restrict__ Wqt,
    const short* __restrict__ W2a, const float* __restrict__ Ksb,
    const float* __restrict__ g, const float* __restrict__ bv,
    short* __restrict__ Mo)
{
    __shared__ short Al[4096];      // [64][64]  (x tile, then Qz slices)
    __shared__ short Bl[16384];     // [256][64] (Wqt, then W2a slices)
    __shared__ float redS[8][64], redQ[8][64];
    const int tid  = threadIdx.x;
    const int lane = tid & 63;
    const int wave = tid >> 6;          // 0..7 = head / col-slice owner
    const int l15  = lane & 15;
    const int kg   = lane >> 4;
    const int srow = tid >> 3;          // 0..63
    const int sc   = tid & 7;
    const int bm   = blockIdx.x * 64;
    const int b    = bm >> 14;          // batch

    // ---- stage 1: Q = x @ Wqt  (K=256; wave owns cols wave*32..+32) ----
    f32x4 accq[4][2];
    #pragma unroll
    for (int m = 0; m < 4; m++)
        #pragma unroll
        for (int n = 0; n < 2; n++)
            accq[m][n] = (f32x4){0.f, 0.f, 0.f, 0.f};

    for (int k0 = 0; k0 < 256; k0 += 64) {
        __syncthreads();
        {   // A: 64 rows of x
            int row = srow;
            int cp  = sc ^ (row & 7);
            gload16(xb + (size_t)(bm + row) * 256 + k0 + cp * 8,
                    &Al[(wave * 64) * 8]);
        }
        #pragma unroll
        for (int q = 0; q < 4; q++) {       // B: 256 rows of Wqt
            int row = q * 64 + srow;
            int cp  = sc ^ (row & 7);
            gload16(Wqt + (size_t)row * 256 + k0 + cp * 8,
                    &Bl[(q * 512 + wave * 64) * 8]);
        }
        __syncthreads();
        #pragma unroll
        for (int ks = 0; ks < 2; ks++) {
            short8v afr[4], bfr[2];
            #pragma unroll
            for (int m = 0; m < 4; m++) {
                int R = m * 16 + l15;
                afr[m] = *reinterpret_cast<const short8v*>(
                    &Al[R * 64 + (((ks * 4 + kg) ^ (R & 7)) * 8)]);
            }
            #pragma unroll
            for (int n = 0; n < 2; n++) {
                int R = wave * 32 + n * 16 + l15;
                bfr[n] = *reinterpret_cast<const short8v*>(
                    &Bl[R * 64 + (((ks * 4 + kg) ^ (R & 7)) * 8)]);
            }
            #pragma unroll
            for (int m = 0; m < 4; m++)
                #pragma unroll
                for (int n = 0; n < 2; n++)
                    accq[m][n] = __builtin_amdgcn_mfma_f32_16x16x32_bf16(
                        afr[m], bfr[n], accq[m][n], 0, 0, 0);
        }
    }

    // ---- Z epilogue: wave == head; elu+1 (fast exp2), Z (fast rcp) ----
    float Ksf[2];
    #pragma unroll
    for (int n = 0; n < 2; n++)
        Ksf[n] = Ksb[b * 256 + wave * 32 + n * 16 + l15];
    #pragma unroll
    for (int m = 0; m < 4; m++)
        #pragma unroll
        for (int n = 0; n < 2; n++)
            #pragma unroll
            for (int j = 0; j < 4; j++) {
                float c = accq[m][n][j];
                accq[m][n][j] = c > 0.f ? c + 1.f : fexp(c);   // elu+1
            }
    #pragma unroll
    for (int m = 0; m < 4; m++)
        #pragma unroll
        for (int j = 0; j < 4; j++) {
            float part = accq[m][0][j] * Ksf[0] + accq[m][1][j] * Ksf[1];
            part += __shfl_xor(part, 1, 64);
            part += __shfl_xor(part, 2, 64);
            part += __shfl_xor(part, 4, 64);
            part += __shfl_xor(part, 8, 64);
            float z = 4096.f * frcp(part + 1e-6f);
            accq[m][0][j] *= z;
            accq[m][1][j] *= z;
        }
    // pack Qz to bf16 (accq dead after this)
    unsigned pq[4][2][2];
    #pragma unroll
    for (int m = 0; m < 4; m++)
        #pragma unroll
        for (int n = 0; n < 2; n++)
            #pragma unroll
            for (int p = 0; p < 2; p++)
                pq[m][n][p] =
                    ((unsigned)(unsigned short)f2bf(accq[m][n][2 * p + 1]) << 16)
                    | (unsigned)(unsigned short)f2bf(accq[m][n][2 * p]);

    // ---- stage 2: P = Qz @ W2a[b]  (4 slices of K=64) ----
    f32x4 accp[4][2];
    #pragma unroll
    for (int m = 0; m < 4; m++)
        #pragma unroll
        for (int n = 0; n < 2; n++)
            accp[m][n] = (f32x4){0.f, 0.f, 0.f, 0.f};

    const short* W2b = W2a + ((size_t)b << 16);
    #pragma unroll
    for (int kk = 0; kk < 4; kk++) {
        __syncthreads();                    // prior slice reads done
        if ((wave >> 1) == kk) {            // 2 owning waves write halves
            #pragma unroll
            for (int m = 0; m < 4; m++)
                #pragma unroll
                for (int n = 0; n < 2; n++) {
                    int c  = (wave & 1) * 4 + n * 2 + (l15 >> 3);
                    int cb = (l15 & 7);
                    #pragma unroll
                    for (int j = 0; j < 4; j++) {
                        int R = m * 16 + kg * 4 + j;
                        Al[R * 64 + ((c ^ (R & 7)) << 3) + cb] =
                            (short)(pq[m][n][j >> 1] >> ((j & 1) * 16));
                    }
                }
        }
        #pragma unroll
        for (int q = 0; q < 4; q++) {       // stage W2a slice: 256 n-rows
            int row = q * 64 + srow;
            int cp  = sc ^ (row & 7);
            gload16(W2b + (size_t)row * 256 + kk * 64 + cp * 8,
                    &Bl[(q * 512 + wave * 64) * 8]);
        }
        __syncthreads();
        #pragma unroll
        for (int ks = 0; ks < 2; ks++) {
            short8v afr[4], bfr[2];
            #pragma unroll
            for (int m = 0; m < 4; m++) {
                int R = m * 16 + l15;
                afr[m] = *reinterpret_cast<const short8v*>(
                    &Al[R * 64 + (((ks * 4 + kg) ^ (R & 7)) * 8)]);
            }
            #pragma unroll
            for (int n = 0; n < 2; n++) {
                int R = wave * 32 + n * 16 + l15;
                bfr[n] = *reinterpret_cast<const short8v*>(
                    &Bl[R * 64 + (((ks * 4 + kg) ^ (R & 7)) * 8)]);
            }
            #pragma unroll
            for (int m = 0; m < 4; m++)
                #pragma unroll
                for (int n = 0; n < 2; n++)
                    accp[m][n] = __builtin_amdgcn_mfma_f32_16x16x32_bf16(
                        afr[m], bfr[n], accp[m][n], 0, 0, 0);
        }
    }

    // ---- LN1 epilogue -> msg_ln bf16 ----
    #pragma unroll
    for (int m = 0; m < 4; m++)
        #pragma unroll
        for (int j = 0; j < 4; j++) {
            float s1 = 0.f, s2 = 0.f;
            #pragma unroll
            for (int n = 0; n < 2; n++) {
                float v = accp[m][n][j];
                s1 += v; s2 += v * v;
            }
            s1 += __shfl_xor(s1, 1, 64); s2 += __shfl_xor(s2, 1, 64);
            s1 += __shfl_xor(s1, 2, 64); s2 += __shfl_xor(s2, 2, 64);
            s1 += __shfl_xor(s1, 4, 64); s2 += __shfl_xor(s2, 4, 64);
            s1 += __shfl_xor(s1, 8, 64); s2 += __shfl_xor(s2, 8, 64);
            if (l15 == 0) {
                int row = m * 16 + kg * 4 + j;
                redS[wave][row] = s1;
                redQ[wave][row] = s2;
            }
        }
    __syncthreads();

    float gc[2], bc[2];
    #pragma unroll
    for (int n = 0; n < 2; n++) {
        int col = wave * 32 + n * 16 + l15;
        gc[n] = g[col]; bc[n] = bv[col];
    }
    #pragma unroll
    for (int m = 0; m < 4; m++)
        #pragma unroll
        for (int j = 0; j < 4; j++) {
            int row = m * 16 + kg * 4 + j;
            float s1 = 0.f, s2 = 0.f;
            #pragma unroll
            for (int w = 0; w < 8; w++) { s1 += redS[w][row]; s2 += redQ[w][row]; }
            float mean = s1 * (1.f / 256.f);
            float var  = s2 * (1.f / 256.f) - mean * mean;
            float inv  = rsqrtf(var + 1e-5f);
            #pragma unroll
            for (int n = 0; n < 2; n++) {
                int col = wave * 32 + n * 16 + l15;
                float o = (accp[m][n][j] - mean) * inv * gc[n] + bc[n];
                Mo[(size_t)(bm + row) * 256 + col] = f2bf(o);
            }
        }
}

// partial KV over a 128-row s-chunk; KVm fused [row][512].  short4 staging.
__global__ __launch_bounds__(256) void kv_partial(
    const short* __restrict__ KVm,
    float* __restrict__ pKV, float* __restrict__ pKs)
{
    int blk = blockIdx.x;
    int bh = blk >> 5, chunk = blk & 31;
    int b = bh >> 3, h = bh & 7;
    int tid = threadIdx.x;
    int e = tid & 31, dq = tid >> 5;
    __shared__ float Ks[16][32], Vs[16][32];
    float acc[4] = {0.f, 0.f, 0.f, 0.f};
    float ks = 0.f;
    const size_t base = ((size_t)b * 4096 + chunk * 128) * 512 + h * 32;

    const int lr  = (tid & 127) >> 3;   // 0..15 row
    const int lq  = tid & 7;            // 0..7 quad
    const int isV = tid >> 7;           // 0=K, 1=V

    for (int s0 = 0; s0 < 128; s0 += 16) {
        short4 v4 = *reinterpret_cast<const short4*>(
            &KVm[base + (size_t)(s0 + lr) * 512 + isV * 256 + lq * 4]);
        float* dst = isV ? &Vs[lr][lq * 4] : &Ks[lr][lq * 4];
        dst[0] = bf2f(v4.x); dst[1] = bf2f(v4.y);
        dst[2] = bf2f(v4.z); dst[3] = bf2f(v4.w);
        __syncthreads();
        #pragma unroll
        for (int sr = 0; sr < 16; sr++) {
            float vv = Vs[sr][e];
            #pragma unroll
            for (int i = 0; i < 4; i++)
                acc[i] = fmaf(Ks[sr][dq * 4 + i], vv, acc[i]);
        }
        if (tid < 32) {
            #pragma unroll
            for (int sr = 0; sr < 16; sr++) ks += Ks[sr][tid];
        }
        __syncthreads();
    }
    #pragma unroll
    for (int i = 0; i < 4; i++)
        pKV[(size_t)blk * 1024 + (dq * 4 + i) * 32 + e] = acc[i];
    if (tid < 32) pKs[blk * 32 + tid] = ks;
}

// reduce 32 chunks -> KV[bh][1024], Ksum[bh][32]
__global__ __launch_bounds__(256) void kv_reduce(
    const float* __restrict__ pKV, const float* __restrict__ pKs,
    float* __restrict__ KV, float* __restrict__ Ksum)
{
    int bh = blockIdx.x;
    int tid = threadIdx.x;
    float s0 = 0.f, s1 = 0.f, s2 = 0.f, s3 = 0.f;
    for (int c = 0; c < 32; c++) {
        const float* p = &pKV[(size_t)(bh * 32 + c) * 1024];
        s0 += p[tid]; s1 += p[tid + 256]; s2 += p[tid + 512]; s3 += p[tid + 768];
    }
    KV[bh * 1024 + tid]       = s0;
    KV[bh * 1024 + tid + 256] = s1;
    KV[bh * 1024 + tid + 512] = s2;
    KV[bh * 1024 + tid + 768] = s3;
    if (tid < 32) {
        float s = 0.f;
        for (int c = 0; c < 32; c++) s += pKs[(bh * 32 + c) * 32 + tid];
        Ksum[bh * 32 + tid] = s;
    }
}

extern "C" void kernel_launch(void* const* d_in, const int* in_sizes, int n_in,
                              void* d_out, int out_size, void* d_ws, size_t ws_size,
                              hipStream_t stream) {
    const float* x      = (const float*)d_in[0];
    const float* sr_w   = (const float*)d_in[1];
    const float* sr_b   = (const float*)d_in[2];
    const float* norm_g = (const float*)d_in[3];
    const float* norm_b = (const float*)d_in[4];
    const float* wq     = (const float*)d_in[5];
    const float* wk     = (const float*)d_in[6];
    const float* wv     = (const float*)d_in[7];
    const float* wm     = (const float*)d_in[8];
    const float* mlp_w1 = (const float*)d_in[9];
    const float* mlp_w2 = (const float*)d_in[10];
    const float* n1_g   = (const float*)d_in[11];
    const float* n1_b   = (const float*)d_in[12];
    const float* n2_g   = (const float*)d_in[13];
    const float* n2_b   = (const float*)d_in[14];
    float* out = (float*)d_out;

    // ---- workspace layout (~109 MB of ~256 MiB) ----
    short* Wct = (short*)d_ws;          // [256][1024]
    short* Wqt = Wct + 262144;          // [256][256]
    short* Wkt = Wqt + 65536;           // [256][256]  \ contiguous = [512][256]
    short* Wvt = Wkt + 65536;           // [256][256]  /
    short* W1t = Wvt + 65536;           // [512][512]
    short* W2t = W1t + 262144;          // [256][512]
    short* W2a = W2t + 131072;          // [4][256][256]
    float* KVb = (float*)(W2a + 262144);// 32768 f
    float* Ksb = KVb + 32768;           // 1024 f
    float* pKs = Ksb + 1024;            // 32768 f
    float* pKV = pKs + 32768;           // 1048576 f
    short* xb16 = (short*)(pKV + 1048576);   // [65536][256] 32MB
    short* SCR  = xb16 + 16777216;           // scratch:
    short* xs16 = SCR;                  //   [16384][256] 8MB
    short* KVm  = SCR + 4194304;        //   [16384][512] 16MB fused K|V
    short* Hc   = SCR + 16777216;       // [65536][512] 64MB
    short* Mb16 = (short*)d_out;        // msg_ln bf16 in d_out (overwritten)

    const float inv_S = 1.f / 4096.f;

    // prep: weights + x cast (single launch)
    prep_all<<<5376, 256, 0, stream>>>(
        sr_w, wq, wk, wv, mlp_w1, mlp_w2, x,
        Wct, Wqt, Wkt, Wvt, W1t, W2t, xb16);

    // conv + bias + LN fused -> xs16 (BM64 variant: 256 blocks)
    gemm_ln<GA_CONV, 0, 0, 1, 1><<<256, 512, 0, stream>>>(
        xb16, Wct, sr_b, norm_g, norm_b, nullptr, xs16, 1024);

    // fused K|V GEMM: B = Wkt||Wvt [512][256]
    gemm_bf16<GA_PLAIN, EP_KV, 0><<<dim3(4, 64), 512, 0, stream>>>(
        xs16, nullptr, Wkt, nullptr, KVm, 512, 256, inv_S);

    // KV + Ksum, fold KV@wm -> W2a
    kv_partial<<<1024, 256, 0, stream>>>(KVm, pKV, pKs);
    kv_reduce<<<32, 256, 0, stream>>>(pKV, pKs, KVb, Ksb);
    w2_prep<<<1024, 256, 0, stream>>>(KVb, wm, W2a);

    // FUSED: msg_ln = LN1( (Z.*(elu(x@wq)+1)) @ W2a[b] ) -> Mb16 (d_out)
    gemm_qzw2ln<<<1024, 512, 0, stream>>>(
        xb16, Wqt, W2a, Ksb, n1_g, n1_b, Mb16);

    // h = relu([x|msg_ln] @ w1) -> Hc  (256x128 tiles, XCD-swizzled)
    gemm_bf16<GA_CONCAT, EP_RELU, 0><<<dim3(4, 256), 512, 0, stream>>>(
        xb16, Mb16, W1t, nullptr, Hc, 512, 512, 0.f);

    // out = LN2(h @ w2) + x  (fused; residual read bf16)
    gemm_ln<GA_PLAIN, 0, 1, 0, 0><<<512, 512, 0, stream>>>(
        Hc, W2t, nullptr, n2_g, n2_b, xb16, out, 512);
}

// Round 25
// 214.017 us; speedup vs baseline: 1.0670x; 1.0670x over previous
//
#include <hip/hip_runtime.h>
#include <math.h>

// ---------------------------------------------------------------------------
// GlobalSubSampleAttn round 25 — REVERT to round-23 best (216.7 us).
// Round 24's BM=64 qzw2ln regressed (54.9 -> 70.6us): B-panel staging cost
// scales with grid x panel; halving BM doubled total staging. BM=128 final.
// Pipeline: prep_all -> conv+LN (gemm_ln BM64) -> fused K|V GEMM ->
// kv_partial/reduce -> w2_prep -> FUSED qzw2ln (Q GEMM + Z + @W2a + LN1)
// -> mlp1 (256x128 XCD-swizzled) -> mlp2+LN2+residual (gemm_ln).
// B=4, N=16384, C=256, S=4096, NHEAD=8, D=32
// ---------------------------------------------------------------------------

#define EP_NONE  0
#define EP_BIAS  1
#define EP_ELU1  2
#define EP_SCALE 3
#define EP_RELU  4
#define EP_KV    5

#define GA_PLAIN  0
#define GA_CONV   1
#define GA_CONCAT 2

typedef __attribute__((ext_vector_type(8))) short short8v;   // 8 bf16
typedef __attribute__((ext_vector_type(4))) float f32x4;

__device__ inline short f2bf(float f) {
    unsigned u = __float_as_uint(f);
    u += 0x7FFFu + ((u >> 16) & 1u);      // round-to-nearest-even
    return (short)(u >> 16);
}
__device__ inline float bf2f(short s) {
    return __uint_as_float(((unsigned)(unsigned short)s) << 16);
}
__device__ inline float fexp(float x) {           // fast e^x (x<=0 here)
    return __builtin_amdgcn_exp2f(x * 1.44269504f);
}
__device__ inline float frcp(float x) {           // fast 1/x
    return __builtin_amdgcn_rcpf(x);
}

__device__ inline void gload16(const void* g, void* l) {
    __builtin_amdgcn_global_load_lds(
        (const __attribute__((address_space(1))) void*)g,
        (__attribute__((address_space(3))) void*)l, 16, 0, 0);
}

template<int EPI>
__device__ inline float epilogue(float c, float b, float scale) {
    if (EPI == EP_BIAS)  return c + b;
    if (EPI == EP_ELU1)  return c > 0.f ? c + 1.f : fexp(c);   // elu(c)+1
    if (EPI == EP_SCALE) return c * scale;
    if (EPI == EP_RELU)  return fmaxf(c, 0.f);
    return c;
}

// XCD-chunked bijective swizzle (nwg % 8 == 0 for all our grids)
__device__ inline int xcd_swz(int lid, int nwg) {
    return (lid & 7) * (nwg >> 3) + (lid >> 3);
}

// weights -> bf16 Bt form (bid 0..3327) + x -> bf16 (bid 3328..5375)
__global__ __launch_bounds__(256) void prep_all(
    const float* __restrict__ srw, const float* __restrict__ wq,
    const float* __restrict__ wk,  const float* __restrict__ wv,
    const float* __restrict__ w1,  const float* __restrict__ w2,
    const float* __restrict__ x,
    short* __restrict__ Wct, short* __restrict__ Wqt, short* __restrict__ Wkt,
    short* __restrict__ Wvt, short* __restrict__ W1t, short* __restrict__ W2t,
    short* __restrict__ xb16)
{
    int bid = blockIdx.x, tid = threadIdx.x;
    if (bid < 1024) {                       // conv: [o][k=p*256+ci]
        int idx = bid * 256 + tid;
        int k = idx & 1023, o = idx >> 10;
        int p = k >> 8, ci = k & 255;
        Wct[idx] = f2bf(srw[(o << 10) + (ci << 2) + p]);
    } else if (bid < 1792) {                // wq/wk/wv: [n][k] 256x256
        int which = (bid - 1024) >> 8;
        int idx = ((bid - 1024) & 255) * 256 + tid;
        int n = idx >> 8, k = idx & 255;
        const float* W = which == 0 ? wq : (which == 1 ? wk : wv);
        short* Wt = which == 0 ? Wqt : (which == 1 ? Wkt : Wvt);
        Wt[idx] = f2bf(W[k * 256 + n]);
    } else if (bid < 2816) {                // mlp_w1: [n][k] 512x512
        int idx = (bid - 1792) * 256 + tid;
        int n = idx >> 9, k = idx & 511;
        W1t[idx] = f2bf(w1[k * 512 + n]);
    } else if (bid < 3328) {                // mlp_w2: [n][k] 256x512
        int idx = (bid - 2816) * 256 + tid;
        int n = idx >> 9, k = idx & 511;
        W2t[idx] = f2bf(w2[k * 256 + n]);
    } else {                                // x cast: 2048 blocks, 8 f4/thread
        int cb = bid - 3328;
        #pragma unroll
        for (int j = 0; j < 8; j++) {
            int idx = cb * 2048 + j * 256 + tid;
            float4 v = reinterpret_cast<const float4*>(x)[idx];
            short4 s;
            s.x = f2bf(v.x); s.y = f2bf(v.y);
            s.z = f2bf(v.z); s.w = f2bf(v.w);
            reinterpret_cast<short4*>(xb16)[idx] = s;
        }
    }
}

// W2a[b][n][k=h*32+d] = sum_v KV[b,h,d,v] * wm[h*32+v, n]   (bf16 Bt form)
__global__ __launch_bounds__(256) void w2_prep(
    const float* __restrict__ KVb, const float* __restrict__ wm,
    short* __restrict__ W2a)
{
    int b = blockIdx.x >> 8, n = blockIdx.x & 255;
    int tid = threadIdx.x;                 // = k
    __shared__ float wcol[256];
    wcol[tid] = wm[tid * 256 + n];
    __syncthreads();
    int h = tid >> 5, d = tid & 31;
    const float* kv = &KVb[b * 8192 + h * 1024 + d * 32];
    float s = 0.f;
    #pragma unroll
    for (int v = 0; v < 32; v++) s = fmaf(kv[v], wcol[h * 32 + v], s);
    W2a[((size_t)(b * 256 + n) << 8) + tid] = f2bf(s);
}

// ---------------------------------------------------------------------------
// gemm_core v2 (round-14 proven): 512 threads, BM=256 x BN=128, 8 waves.
// LDS: A [256][64] 32KB + B [128][64] 16KB.  Swizzled gload_lds + ds_read.
// ---------------------------------------------------------------------------
template<int GATHER, int BB>
__device__ inline void gemm_core(
    const short* __restrict__ Ab, const short* __restrict__ A2b,
    const short* __restrict__ Bt, int K, int bm, int bn,
    short* AlF, short* BlF, f32x4 acc[4][4])
{
    const int tid  = threadIdx.x;          // 0..511
    const int lane = tid & 63;
    const int wave = tid >> 6;             // 0..7
    const int wr   = (wave >> 1) * 64;     // 0,64,128,192
    const int wc   = (wave & 1) * 64;      // 0,64
    const int l15  = lane & 15;
    const int kg   = lane >> 4;
    const int srow = tid >> 3;             // 0..63
    const int sc   = tid & 7;

    if (BB) Bt += (size_t)(bm >> 14) << 16;

    for (int k0 = 0; k0 < K; k0 += 64) {
        __syncthreads();
        #pragma unroll
        for (int q = 0; q < 4; q++) {      // A: 256 rows
            int row = q * 64 + srow;
            int cp  = sc ^ (row & 7);
            const short* ga;
            if (GATHER == GA_PLAIN) {
                ga = Ab + (size_t)(bm + row) * K + k0 + cp * 8;
            } else if (GATHER == GA_CONCAT) {
                const short* base = (k0 < 256) ? Ab : A2b;
                ga = base + ((size_t)(bm + row) << 8) + (k0 & 255) + cp * 8;
            } else { // GA_CONV
                int grow = bm + row;
                int b = grow >> 12, s = grow & 4095;
                int ii = s >> 6, jj = s & 63;
                int p = k0 >> 8;
                int kh = p >> 1, kw = p & 1;
                int pix = (b << 14) + ((2 * ii + kh) << 7) + (2 * jj + kw);
                ga = Ab + ((size_t)pix << 8) + (k0 & 255) + cp * 8;
            }
            gload16(ga, &AlF[(q * 512 + wave * 64) * 8]);
        }
        #pragma unroll
        for (int q = 0; q < 2; q++) {      // B: 128 rows
            int row = q * 64 + srow;
            int cp  = sc ^ (row & 7);
            const short* gb = Bt + (size_t)(bn + row) * K + k0 + cp * 8;
            gload16(gb, &BlF[(q * 512 + wave * 64) * 8]);
        }
        __syncthreads();

        #pragma unroll
        for (int ks = 0; ks < 2; ks++) {
            short8v afr[4], bfr[4];
            #pragma unroll
            for (int m = 0; m < 4; m++) {
                int R = wr + m * 16 + l15;
                afr[m] = *reinterpret_cast<const short8v*>(
                    &AlF[R * 64 + (((ks * 4 + kg) ^ (R & 7)) * 8)]);
            }
            #pragma unroll
            for (int n = 0; n < 4; n++) {
                int R = wc + n * 16 + l15;
                bfr[n] = *reinterpret_cast<const short8v*>(
                    &BlF[R * 64 + (((ks * 4 + kg) ^ (R & 7)) * 8)]);
            }
            #pragma unroll
            for (int m = 0; m < 4; m++)
                #pragma unroll
                for (int n = 0; n < 4; n++)
                    acc[m][n] = __builtin_amdgcn_mfma_f32_16x16x32_bf16(
                        afr[m], bfr[n], acc[m][n], 0, 0, 0);
        }
    }
}

// generic 256x128 GEMM, bf16 output, XCD-swizzled block order (cols fastest)
template<int GATHER, int EPI, int BB>
__global__ __launch_bounds__(512) void gemm_bf16(
    const short* __restrict__ Ab, const short* __restrict__ A2b,
    const short* __restrict__ Bt, const float* __restrict__ bias,
    short* __restrict__ Cb, int N, int K, float scale)
{
    __shared__ short AlF[16384];   // [256][64]
    __shared__ short BlF[8192];    // [128][64]
    const int nwg = gridDim.x * gridDim.y;
    const int lid = blockIdx.y * gridDim.x + blockIdx.x;
    const int swz = xcd_swz(lid, nwg);
    const int bn  = (swz % gridDim.x) * 128;   // col = fast index
    const int bm  = (swz / gridDim.x) * 256;
    f32x4 acc[4][4];
    #pragma unroll
    for (int m = 0; m < 4; m++)
        #pragma unroll
        for (int n = 0; n < 4; n++)
            acc[m][n] = (f32x4){0.f, 0.f, 0.f, 0.f};

    gemm_core<GATHER, BB>(Ab, A2b, Bt, K, bm, bn, AlF, BlF, acc);

    const int lane = threadIdx.x & 63;
    const int wave = threadIdx.x >> 6;
    const int wr = (wave >> 1) * 64, wc = (wave & 1) * 64;
    const int l15 = lane & 15, r0 = (lane >> 4) * 4;
    #pragma unroll
    for (int n = 0; n < 4; n++) {
        int col = bn + wc + n * 16 + l15;
        float bb = (EPI == EP_BIAS) ? bias[col] : 0.f;
        #pragma unroll
        for (int m = 0; m < 4; m++) {
            int rowb = bm + wr + m * 16 + r0;
            #pragma unroll
            for (int j = 0; j < 4; j++) {
                float c = acc[m][n][j];
                float o;
                if (EPI == EP_KV)
                    o = (bn < 256) ? (c > 0.f ? c + 1.f : fexp(c)) : c * scale;
                else
                    o = epilogue<EPI>(c, bb, scale);
                Cb[(size_t)(rowb + j) * N + col] = f2bf(o);
            }
        }
    }
}

// ---------------------------------------------------------------------------
// gemm_ln v5: 512 threads, BN=256 (full row) + fused LayerNorm epilogue.
//   BM64=0: BM=128, 8 waves (2 row x 4 col), acc[4][4]   (mlp2)
//   BM64=1: BM=64,  8 waves (1 row x 8 col-32), acc[4][2] (conv: grid 2x)
//   FIN=0: out bf16 = LN(acc[+bias]);  FIN=1: out f32 = LN(acc)+bf2f(res16)
// ---------------------------------------------------------------------------
template<int GATHER, int BB, int FIN, int BIAS, int BM64>
__global__ __launch_bounds__(512) void gemm_ln(
    const short* __restrict__ Ab, const short* __restrict__ Bt,
    const float* __restrict__ bias,
    const float* __restrict__ g, const float* __restrict__ bv,
    const short* __restrict__ res16, void* __restrict__ Co, int K)
{
    constexpr int BM  = BM64 ? 64 : 128;
    constexpr int NFR = BM64 ? 2 : 4;          // col frags per wave
    constexpr int NW  = BM64 ? 8 : 4;          // waves sharing a row
    __shared__ short Al[BM * 64];              // [BM][64]
    __shared__ short Bl[16384];                // [256][64]
    __shared__ float redS[NW][BM], redQ[NW][BM];
    const int tid  = threadIdx.x;
    const int lane = tid & 63;
    const int wave = tid >> 6;                 // 0..7
    const int wr   = BM64 ? 0 : (wave >> 2) * 64;
    const int wcid = BM64 ? wave : (wave & 3);
    const int cw   = BM64 ? 32 : 64;           // cols per wave
    const int l15  = lane & 15;
    const int kg   = lane >> 4;
    const int srow = tid >> 3;                 // 0..63
    const int sc   = tid & 7;
    const int bm   = blockIdx.x * BM;
    const short* Bp = BB ? Bt + ((size_t)(bm >> 14) << 16) : Bt;

    f32x4 acc[4][NFR];
    #pragma unroll
    for (int m = 0; m < 4; m++)
        #pragma unroll
        for (int n = 0; n < NFR; n++)
            acc[m][n] = (f32x4){0.f, 0.f, 0.f, 0.f};

    for (int k0 = 0; k0 < K; k0 += 64) {
        __syncthreads();
        #pragma unroll
        for (int q = 0; q < BM / 64; q++) {    // A: BM rows
            int row = q * 64 + srow;
            int cp  = sc ^ (row & 7);
            const short* ga;
            if (GATHER == GA_CONV) {
                int grow = bm + row;
                int b = grow >> 12, s = grow & 4095;
                int ii = s >> 6, jj = s & 63;
                int p = k0 >> 8;
                int kh = p >> 1, kw = p & 1;
                int pix = (b << 14) + ((2 * ii + kh) << 7) + (2 * jj + kw);
                ga = Ab + ((size_t)pix << 8) + (k0 & 255) + cp * 8;
            } else {
                ga = Ab + (size_t)(bm + row) * K + k0 + cp * 8;
            }
            gload16(ga, &Al[(q * 512 + wave * 64) * 8]);
        }
        #pragma unroll
        for (int q = 0; q < 4; q++) {          // B: 256 rows
            int row = q * 64 + srow;
            int cp  = sc ^ (row & 7);
            gload16(Bp + (size_t)row * K + k0 + cp * 8,
                    &Bl[(q * 512 + wave * 64) * 8]);
        }
        __syncthreads();

        #pragma unroll
        for (int ks = 0; ks < 2; ks++) {
            short8v afr[4], bfr[NFR];
            #pragma unroll
            for (int m = 0; m < 4; m++) {
                int R = wr + m * 16 + l15;
                afr[m] = *reinterpret_cast<const short8v*>(
                    &Al[R * 64 + (((ks * 4 + kg) ^ (R & 7)) * 8)]);
            }
            #pragma unroll
            for (int n = 0; n < NFR; n++) {
                int R = wcid * cw + n * 16 + l15;
                bfr[n] = *reinterpret_cast<const short8v*>(
                    &Bl[R * 64 + (((ks * 4 + kg) ^ (R & 7)) * 8)]);
            }
            #pragma unroll
            for (int m = 0; m < 4; m++)
                #pragma unroll
                for (int n = 0; n < NFR; n++)
                    acc[m][n] = __builtin_amdgcn_mfma_f32_16x16x32_bf16(
                        afr[m], bfr[n], acc[m][n], 0, 0, 0);
        }
    }

    // ---- optional bias (pre-LN) ----
    if (BIAS) {
        #pragma unroll
        for (int n = 0; n < NFR; n++) {
            float bb = bias[wcid * cw + n * 16 + l15];
            #pragma unroll
            for (int m = 0; m < 4; m++)
                #pragma unroll
                for (int j = 0; j < 4; j++)
                    acc[m][n][j] += bb;
        }
    }

    // ---- fused LayerNorm epilogue ----
    #pragma unroll
    for (int m = 0; m < 4; m++)
        #pragma unroll
        for (int j = 0; j < 4; j++) {
            float s1 = 0.f, s2 = 0.f;
            #pragma unroll
            for (int n = 0; n < NFR; n++) {
                float v = acc[m][n][j];
                s1 += v; s2 += v * v;
            }
            s1 += __shfl_xor(s1, 1, 64); s2 += __shfl_xor(s2, 1, 64);
            s1 += __shfl_xor(s1, 2, 64); s2 += __shfl_xor(s2, 2, 64);
            s1 += __shfl_xor(s1, 4, 64); s2 += __shfl_xor(s2, 4, 64);
            s1 += __shfl_xor(s1, 8, 64); s2 += __shfl_xor(s2, 8, 64);
            if (l15 == 0) {
                int row = wr + m * 16 + kg * 4 + j;
                redS[wcid][row] = s1;
                redQ[wcid][row] = s2;
            }
        }
    __syncthreads();

    float gc[NFR], bc[NFR];
    #pragma unroll
    for (int n = 0; n < NFR; n++) {
        int col = wcid * cw + n * 16 + l15;
        gc[n] = g[col]; bc[n] = bv[col];
    }
    #pragma unroll
    for (int m = 0; m < 4; m++)
        #pragma unroll
        for (int j = 0; j < 4; j++) {
            int row = wr + m * 16 + kg * 4 + j;
            float s1 = 0.f, s2 = 0.f;
            #pragma unroll
            for (int w = 0; w < NW; w++) { s1 += redS[w][row]; s2 += redQ[w][row]; }
            float mean = s1 * (1.f / 256.f);
            float var  = s2 * (1.f / 256.f) - mean * mean;
            float inv  = rsqrtf(var + 1e-5f);
            #pragma unroll
            for (int n = 0; n < NFR; n++) {
                int col = wcid * cw + n * 16 + l15;
                float o = (acc[m][n][j] - mean) * inv * gc[n] + bc[n];
                size_t gi = (size_t)(bm + row) * 256 + col;
                if (FIN) ((float*)Co)[gi] = o + bf2f(res16[gi]);
                else     ((short*)Co)[gi] = f2bf(o);
            }
        }
}

// ---------------------------------------------------------------------------
// gemm_qzw2ln: FUSED  Qz = Z.*(elu(x@Wqt)+1)  ->  P = Qz @ W2a[b]  -> LN1
// 512 threads, BM=128 rows/block, BN=256 (full row), 8 waves (2 row x 4 col).
// ---------------------------------------------------------------------------
__global__ __launch_bounds__(512) void gemm_qzw2ln(
    const short* __restrict__ xb, const short* __restrict__ Wqt,
    const short* __restrict__ W2a, const float* __restrict__ Ksb,
    const float* __restrict__ g, const float* __restrict__ bv,
    short* __restrict__ Mo)
{
    __shared__ short Al[8192];      // [128][64]  (x tile, then Qz slices)
    __shared__ short Bl[16384];     // [256][64]  (Wqt, then W2a slices)
    __shared__ float redS[4][128], redQ[4][128];
    const int tid  = threadIdx.x;
    const int lane = tid & 63;
    const int wave = tid >> 6;          // 0..7
    const int wr   = (wave >> 2) * 64;  // row half
    const int wc4  = wave & 3;          // col quarter (64 cols)
    const int l15  = lane & 15;
    const int kg   = lane >> 4;
    const int srow = tid >> 3;          // 0..63
    const int sc   = tid & 7;
    const int bm   = blockIdx.x * 128;
    const int b    = bm >> 14;          // batch

    // ---- stage 1: Q = x @ Wqt  (K=256, full 256-col row) ----
    f32x4 accq[4][4];
    #pragma unroll
    for (int m = 0; m < 4; m++)
        #pragma unroll
        for (int n = 0; n < 4; n++)
            accq[m][n] = (f32x4){0.f, 0.f, 0.f, 0.f};

    for (int k0 = 0; k0 < 256; k0 += 64) {
        __syncthreads();
        #pragma unroll
        for (int q = 0; q < 2; q++) {       // A: 128 rows of x
            int row = q * 64 + srow;
            int cp  = sc ^ (row & 7);
            gload16(xb + (size_t)(bm + row) * 256 + k0 + cp * 8,
                    &Al[(q * 512 + wave * 64) * 8]);
        }
        #pragma unroll
        for (int q = 0; q < 4; q++) {       // B: 256 rows of Wqt
            int row = q * 64 + srow;
            int cp  = sc ^ (row & 7);
            gload16(Wqt + (size_t)row * 256 + k0 + cp * 8,
                    &Bl[(q * 512 + wave * 64) * 8]);
        }
        __syncthreads();
        #pragma unroll
        for (int ks = 0; ks < 2; ks++) {
            short8v afr[4], bfr[4];
            #pragma unroll
            for (int m = 0; m < 4; m++) {
                int R = wr + m * 16 + l15;
                afr[m] = *reinterpret_cast<const short8v*>(
                    &Al[R * 64 + (((ks * 4 + kg) ^ (R & 7)) * 8)]);
            }
            #pragma unroll
            for (int n = 0; n < 4; n++) {
                int R = wc4 * 64 + n * 16 + l15;
                bfr[n] = *reinterpret_cast<const short8v*>(
                    &Bl[R * 64 + (((ks * 4 + kg) ^ (R & 7)) * 8)]);
            }
            #pragma unroll
            for (int m = 0; m < 4; m++)
                #pragma unroll
                for (int n = 0; n < 4; n++)
                    accq[m][n] = __builtin_amdgcn_mfma_f32_16x16x32_bf16(
                        afr[m], bfr[n], accq[m][n], 0, 0, 0);
        }
    }

    // ---- Z epilogue: elu+1 (fast exp2), per-(row,head) Z (fast rcp) ----
    float Ksf[4];
    #pragma unroll
    for (int n = 0; n < 4; n++)
        Ksf[n] = Ksb[b * 256 + wc4 * 64 + n * 16 + l15];
    #pragma unroll
    for (int m = 0; m < 4; m++)
        #pragma unroll
        for (int n = 0; n < 4; n++)
            #pragma unroll
            for (int j = 0; j < 4; j++) {
                float c = accq[m][n][j];
                accq[m][n][j] = c > 0.f ? c + 1.f : fexp(c);   // elu+1
            }
    #pragma unroll
    for (int hh = 0; hh < 2; hh++) {
        #pragma unroll
        for (int m = 0; m < 4; m++)
            #pragma unroll
            for (int j = 0; j < 4; j++) {
                float part = accq[m][2 * hh][j] * Ksf[2 * hh]
                           + accq[m][2 * hh + 1][j] * Ksf[2 * hh + 1];
                part += __shfl_xor(part, 1, 64);
                part += __shfl_xor(part, 2, 64);
                part += __shfl_xor(part, 4, 64);
                part += __shfl_xor(part, 8, 64);
                float z = 4096.f * frcp(part + 1e-6f);
                accq[m][2 * hh][j]     *= z;
                accq[m][2 * hh + 1][j] *= z;
            }
    }
    // pack Qz to bf16 (accq dead after this)
    unsigned pq[4][4][2];
    #pragma unroll
    for (int m = 0; m < 4; m++)
        #pragma unroll
        for (int n = 0; n < 4; n++)
            #pragma unroll
            for (int p = 0; p < 2; p++)
                pq[m][n][p] =
                    ((unsigned)(unsigned short)f2bf(accq[m][n][2 * p + 1]) << 16)
                    | (unsigned)(unsigned short)f2bf(accq[m][n][2 * p]);

    // ---- stage 2: P = Qz @ W2a[b]  (4 slices of K=64) ----
    f32x4 accp[4][4];
    #pragma unroll
    for (int m = 0; m < 4; m++)
        #pragma unroll
        for (int n = 0; n < 4; n++)
            accp[m][n] = (f32x4){0.f, 0.f, 0.f, 0.f};

    const short* W2b = W2a + ((size_t)b << 16);
    #pragma unroll
    for (int kk = 0; kk < 4; kk++) {
        __syncthreads();                    // prior slice reads done
        if (wc4 == kk) {                    // owning col-wave writes Qz slice
            #pragma unroll
            for (int m = 0; m < 4; m++)
                #pragma unroll
                for (int n = 0; n < 4; n++) {
                    int c = n * 2 + (l15 >> 3);       // 16B chunk in slice
                    int cb = (l15 & 7);               // elem in chunk
                    #pragma unroll
                    for (int j = 0; j < 4; j++) {
                        int R = wr + m * 16 + kg * 4 + j;
                        Al[R * 64 + ((c ^ (R & 7)) << 3) + cb] =
                            (short)(pq[m][n][j >> 1] >> ((j & 1) * 16));
                    }
                }
        }
        #pragma unroll
        for (int q = 0; q < 4; q++) {       // stage W2a slice: 256 n-rows
            int row = q * 64 + srow;
            int cp  = sc ^ (row & 7);
            gload16(W2b + (size_t)row * 256 + kk * 64 + cp * 8,
                    &Bl[(q * 512 + wave * 64) * 8]);
        }
        __syncthreads();
        #pragma unroll
        for (int ks = 0; ks < 2; ks++) {
            short8v afr[4], bfr[4];
            #pragma unroll
            for (int m = 0; m < 4; m++) {
                int R = wr + m * 16 + l15;
                afr[m] = *reinterpret_cast<const short8v*>(
                    &Al[R * 64 + (((ks * 4 + kg) ^ (R & 7)) * 8)]);
            }
            #pragma unroll
            for (int n = 0; n < 4; n++) {
                int R = wc4 * 64 + n * 16 + l15;
                bfr[n] = *reinterpret_cast<const short8v*>(
                    &Bl[R * 64 + (((ks * 4 + kg) ^ (R & 7)) * 8)]);
            }
            #pragma unroll
            for (int m = 0; m < 4; m++)
                #pragma unroll
                for (int n = 0; n < 4; n++)
                    accp[m][n] = __builtin_amdgcn_mfma_f32_16x16x32_bf16(
                        afr[m], bfr[n], accp[m][n], 0, 0, 0);
        }
    }

    // ---- LN1 epilogue -> msg_ln bf16 ----
    #pragma unroll
    for (int m = 0; m < 4; m++)
        #pragma unroll
        for (int j = 0; j < 4; j++) {
            float s1 = 0.f, s2 = 0.f;
            #pragma unroll
            for (int n = 0; n < 4; n++) {
                float v = accp[m][n][j];
                s1 += v; s2 += v * v;
            }
            s1 += __shfl_xor(s1, 1, 64); s2 += __shfl_xor(s2, 1, 64);
            s1 += __shfl_xor(s1, 2, 64); s2 += __shfl_xor(s2, 2, 64);
            s1 += __shfl_xor(s1, 4, 64); s2 += __shfl_xor(s2, 4, 64);
            s1 += __shfl_xor(s1, 8, 64); s2 += __shfl_xor(s2, 8, 64);
            if (l15 == 0) {
                int row = wr + m * 16 + kg * 4 + j;
                redS[wc4][row] = s1;
                redQ[wc4][row] = s2;
            }
        }
    __syncthreads();

    float gc[4], bc[4];
    #pragma unroll
    for (int n = 0; n < 4; n++) {
        int col = wc4 * 64 + n * 16 + l15;
        gc[n] = g[col]; bc[n] = bv[col];
    }
    #pragma unroll
    for (int m = 0; m < 4; m++)
        #pragma unroll
        for (int j = 0; j < 4; j++) {
            int row = wr + m * 16 + kg * 4 + j;
            float mean = (redS[0][row] + redS[1][row] +
                          redS[2][row] + redS[3][row]) * (1.f / 256.f);
            float var  = (redQ[0][row] + redQ[1][row] +
                          redQ[2][row] + redQ[3][row]) * (1.f / 256.f)
                         - mean * mean;
            float inv  = rsqrtf(var + 1e-5f);
            #pragma unroll
            for (int n = 0; n < 4; n++) {
                int col = wc4 * 64 + n * 16 + l15;
                float o = (accp[m][n][j] - mean) * inv * gc[n] + bc[n];
                Mo[(size_t)(bm + row) * 256 + col] = f2bf(o);
            }
        }
}

// partial KV over a 128-row s-chunk; KVm fused [row][512].  short4 staging.
__global__ __launch_bounds__(256) void kv_partial(
    const short* __restrict__ KVm,
    float* __restrict__ pKV, float* __restrict__ pKs)
{
    int blk = blockIdx.x;
    int bh = blk >> 5, chunk = blk & 31;
    int b = bh >> 3, h = bh & 7;
    int tid = threadIdx.x;
    int e = tid & 31, dq = tid >> 5;
    __shared__ float Ks[16][32], Vs[16][32];
    float acc[4] = {0.f, 0.f, 0.f, 0.f};
    float ks = 0.f;
    const size_t base = ((size_t)b * 4096 + chunk * 128) * 512 + h * 32;

    const int lr  = (tid & 127) >> 3;   // 0..15 row
    const int lq  = tid & 7;            // 0..7 quad
    const int isV = tid >> 7;           // 0=K, 1=V

    for (int s0 = 0; s0 < 128; s0 += 16) {
        short4 v4 = *reinterpret_cast<const short4*>(
            &KVm[base + (size_t)(s0 + lr) * 512 + isV * 256 + lq * 4]);
        float* dst = isV ? &Vs[lr][lq * 4] : &Ks[lr][lq * 4];
        dst[0] = bf2f(v4.x); dst[1] = bf2f(v4.y);
        dst[2] = bf2f(v4.z); dst[3] = bf2f(v4.w);
        __syncthreads();
        #pragma unroll
        for (int sr = 0; sr < 16; sr++) {
            float vv = Vs[sr][e];
            #pragma unroll
            for (int i = 0; i < 4; i++)
                acc[i] = fmaf(Ks[sr][dq * 4 + i], vv, acc[i]);
        }
        if (tid < 32) {
            #pragma unroll
            for (int sr = 0; sr < 16; sr++) ks += Ks[sr][tid];
        }
        __syncthreads();
    }
    #pragma unroll
    for (int i = 0; i < 4; i++)
        pKV[(size_t)blk * 1024 + (dq * 4 + i) * 32 + e] = acc[i];
    if (tid < 32) pKs[blk * 32 + tid] = ks;
}

// reduce 32 chunks -> KV[bh][1024], Ksum[bh][32]
__global__ __launch_bounds__(256) void kv_reduce(
    const float* __restrict__ pKV, const float* __restrict__ pKs,
    float* __restrict__ KV, float* __restrict__ Ksum)
{
    int bh = blockIdx.x;
    int tid = threadIdx.x;
    float s0 = 0.f, s1 = 0.f, s2 = 0.f, s3 = 0.f;
    for (int c = 0; c < 32; c++) {
        const float* p = &pKV[(size_t)(bh * 32 + c) * 1024];
        s0 += p[tid]; s1 += p[tid + 256]; s2 += p[tid + 512]; s3 += p[tid + 768];
    }
    KV[bh * 1024 + tid]       = s0;
    KV[bh * 1024 + tid + 256] = s1;
    KV[bh * 1024 + tid + 512] = s2;
    KV[bh * 1024 + tid + 768] = s3;
    if (tid < 32) {
        float s = 0.f;
        for (int c = 0; c < 32; c++) s += pKs[(bh * 32 + c) * 32 + tid];
        Ksum[bh * 32 + tid] = s;
    }
}

extern "C" void kernel_launch(void* const* d_in, const int* in_sizes, int n_in,
                              void* d_out, int out_size, void* d_ws, size_t ws_size,
                              hipStream_t stream) {
    const float* x      = (const float*)d_in[0];
    const float* sr_w   = (const float*)d_in[1];
    const float* sr_b   = (const float*)d_in[2];
    const float* norm_g = (const float*)d_in[3];
    const float* norm_b = (const float*)d_in[4];
    const float* wq     = (const float*)d_in[5];
    const float* wk     = (const float*)d_in[6];
    const float* wv     = (const float*)d_in[7];
    const float* wm     = (const float*)d_in[8];
    const float* mlp_w1 = (const float*)d_in[9];
    const float* mlp_w2 = (const float*)d_in[10];
    const float* n1_g   = (const float*)d_in[11];
    const float* n1_b   = (const float*)d_in[12];
    const float* n2_g   = (const float*)d_in[13];
    const float* n2_b   = (const float*)d_in[14];
    float* out = (float*)d_out;

    // ---- workspace layout (~109 MB of ~256 MiB) ----
    short* Wct = (short*)d_ws;          // [256][1024]
    short* Wqt = Wct + 262144;          // [256][256]
    short* Wkt = Wqt + 65536;           // [256][256]  \ contiguous = [512][256]
    short* Wvt = Wkt + 65536;           // [256][256]  /
    short* W1t = Wvt + 65536;           // [512][512]
    short* W2t = W1t + 262144;          // [256][512]
    short* W2a = W2t + 131072;          // [4][256][256]
    float* KVb = (float*)(W2a + 262144);// 32768 f
    float* Ksb = KVb + 32768;           // 1024 f
    float* pKs = Ksb + 1024;            // 32768 f
    float* pKV = pKs + 32768;           // 1048576 f
    short* xb16 = (short*)(pKV + 1048576);   // [65536][256] 32MB
    short* SCR  = xb16 + 16777216;           // scratch:
    short* xs16 = SCR;                  //   [16384][256] 8MB
    short* KVm  = SCR + 4194304;        //   [16384][512] 16MB fused K|V
    short* Hc   = SCR + 16777216;       // [65536][512] 64MB
    short* Mb16 = (short*)d_out;        // msg_ln bf16 in d_out (overwritten)

    const float inv_S = 1.f / 4096.f;

    // prep: weights + x cast (single launch)
    prep_all<<<5376, 256, 0, stream>>>(
        sr_w, wq, wk, wv, mlp_w1, mlp_w2, x,
        Wct, Wqt, Wkt, Wvt, W1t, W2t, xb16);

    // conv + bias + LN fused -> xs16 (BM64 variant: 256 blocks)
    gemm_ln<GA_CONV, 0, 0, 1, 1><<<256, 512, 0, stream>>>(
        xb16, Wct, sr_b, norm_g, norm_b, nullptr, xs16, 1024);

    // fused K|V GEMM: B = Wkt||Wvt [512][256]
    gemm_bf16<GA_PLAIN, EP_KV, 0><<<dim3(4, 64), 512, 0, stream>>>(
        xs16, nullptr, Wkt, nullptr, KVm, 512, 256, inv_S);

    // KV + Ksum, fold KV@wm -> W2a
    kv_partial<<<1024, 256, 0, stream>>>(KVm, pKV, pKs);
    kv_reduce<<<32, 256, 0, stream>>>(pKV, pKs, KVb, Ksb);
    w2_prep<<<1024, 256, 0, stream>>>(KVb, wm, W2a);

    // FUSED: msg_ln = LN1( (Z.*(elu(x@wq)+1)) @ W2a[b] ) -> Mb16 (d_out)
    gemm_qzw2ln<<<512, 512, 0, stream>>>(
        xb16, Wqt, W2a, Ksb, n1_g, n1_b, Mb16);

    // h = relu([x|msg_ln] @ w1) -> Hc  (256x128 tiles, XCD-swizzled)
    gemm_bf16<GA_CONCAT, EP_RELU, 0><<<dim3(4, 256), 512, 0, stream>>>(
        xb16, Mb16, W1t, nullptr, Hc, 512, 512, 0.f);

    // out = LN2(h @ w2) + x  (fused; residual read bf16)
    gemm_ln<GA_PLAIN, 0, 1, 0, 0><<<512, 512, 0, stream>>>(
        Hc, W2t, nullptr, n2_g, n2_b, xb16, out, 512);
}